// Round 7
// baseline (1678.742 us; speedup 1.0000x reference)
//
#include <hip/hip_runtime.h>
#include <hip/hip_bf16.h>
#include <stdint.h>

#define VOCAB 50257
#define VPAD  50432   /* 394*128 */
#define DIM   640
#define SEQ   256
#define NBATCH 16
#define MROWS 4096    /* NBATCH*SEQ */

using bf16 = __hip_bfloat16;
typedef __attribute__((ext_vector_type(8))) short short8;
typedef __attribute__((ext_vector_type(4))) float f32x4;
struct bf16x4 { bf16 a, b, c, d; };

__device__ __forceinline__ void gld_lds16(const void* g, void* l) {
  __builtin_amdgcn_global_load_lds(
      (const __attribute__((address_space(1))) void*)g,
      (__attribute__((address_space(3))) void*)l, 16, 0, 0);
}

#define BAR() asm volatile("s_barrier" ::: "memory")
#define VMC0() asm volatile("s_waitcnt vmcnt(0)" ::: "memory")

// ---------------- embed: x = w_embed[idx] + w_pos  -> bf16 ----------------
__global__ void embed_kernel(const int* __restrict__ idx,
                             const float* __restrict__ we,
                             const float* __restrict__ wp,
                             bf16* __restrict__ xb) {
  int row = blockIdx.x;
  int t = row & (SEQ - 1);
  int tok = idx[row];
  const float* src = we + (long)tok * DIM;
  const float* pos = wp + (long)t * DIM;
  for (int d = threadIdx.x * 4; d < DIM; d += blockDim.x * 4) {
    float4 s = *(const float4*)(src + d);
    float4 p = *(const float4*)(pos + d);
    bf16x4 o = { __float2bfloat16(s.x + p.x), __float2bfloat16(s.y + p.y),
                 __float2bfloat16(s.z + p.z), __float2bfloat16(s.w + p.w) };
    *(bf16x4*)(xb + (long)row * DIM + d) = o;
  }
}

// ---------------- f32 -> bf16 convert (x4) with zero tail pad ----------------
__global__ void conv4_kernel(const float* __restrict__ src, bf16* __restrict__ dst,
                             long n_src, long n_dst) {
  long i = ((long)blockIdx.x * blockDim.x + threadIdx.x) * 4;
  long stride = (long)gridDim.x * blockDim.x * 4;
  for (; i < n_dst; i += stride) {
    float4 v = (i < n_src) ? *(const float4*)(src + i) : make_float4(0.f, 0.f, 0.f, 0.f);
    bf16x4 o = { __float2bfloat16(v.x), __float2bfloat16(v.y),
                 __float2bfloat16(v.z), __float2bfloat16(v.w) };
    *(bf16x4*)(dst + i) = o;
  }
}

// ---------------- v (16*256,640) -> vT (16,640,256) ----------------
__global__ void transpose_v(const bf16* __restrict__ v, bf16* __restrict__ vt) {
  long i = (long)blockIdx.x * blockDim.x + threadIdx.x;
  if (i >= (long)NBATCH * DIM * SEQ) return;
  int t = (int)(i & (SEQ - 1));
  long be = i >> 8;
  int e = (int)(be % DIM);
  int b = (int)(be / DIM);
  vt[i] = v[((long)b * SEQ + t) * DIM + e];
}

// ---------------- causal softmax: scores f32 -> P bf16 ----------------
__global__ void softmax_kernel(const float* __restrict__ sc, bf16* __restrict__ p) {
  int wid = threadIdx.x >> 6, lane = threadIdx.x & 63;
  int row = blockIdx.x * 4 + wid;
  int t = row & (SEQ - 1);
  const float* srow = sc + (long)row * SEQ;
  const float rsc = 0.03952847075210474f;  // 1/sqrt(640)
  float v[4];
  float mx = -1e30f;
#pragma unroll
  for (int i = 0; i < 4; ++i) {
    int s = lane + 64 * i;
    v[i] = (s <= t) ? srow[s] * rsc : -1e30f;
    mx = fmaxf(mx, v[i]);
  }
#pragma unroll
  for (int off = 32; off; off >>= 1) mx = fmaxf(mx, __shfl_xor(mx, off, 64));
  float sum = 0.f;
#pragma unroll
  for (int i = 0; i < 4; ++i) {
    int s = lane + 64 * i;
    v[i] = (s <= t) ? __expf(v[i] - mx) : 0.f;
    sum += v[i];
  }
#pragma unroll
  for (int off = 32; off; off >>= 1) sum += __shfl_xor(sum, off, 64);
  float inv = 1.f / sum;
#pragma unroll
  for (int i = 0; i < 4; ++i)
    p[(long)row * SEQ + lane + 64 * i] = __float2bfloat16(v[i] * inv);
}

// ========= 128x128 GEMM, 2-slot depth-1 pipeline: C = A * B^T (+bias) =========
// A: (Mtiles*128, K) bf16, B: (Ntiles*128, K) bf16, row-major.
// 4 waves (2Mx2N), per-wave 64x64 (acc[4][4]). BK=32. 2-slot LDS ring (32 KiB).
// Per tile: {STAGE next -> other slot; ds_read cur; MFMA; vmcnt(0); s_barrier}.
// Natural grid order (r4: XCD swizzle thrashed L3, FETCH 272MB->1GB).
// 16B-block LDS swizzle sigma(beta)=beta^((beta>>3)&3) both-sides (verified
// SQ_LDS_BANK_CONFLICT=0 r4/r5).
// f32 epilogue: per-wave LDS transpose -> dwordx4 stores; NTS=true uses
// NON-TEMPORAL stores (C written-once-never-read; r1-r6 evidence: the 824MB
// C-stream evicts the 64MB B panel from L2/L3 -> FETCH 4x B-size -> staging
// loads become loaded-HBM-latency misses; nt bypasses the caches).
template <int NT, typename OUT_T, bool BIAS, bool NTS>
__global__ __launch_bounds__(256, 4) void gemm_pipe(
    const bf16* __restrict__ Ag, const bf16* __restrict__ Bg,
    OUT_T* __restrict__ Cg, const float* __restrict__ bias,
    int K, int ldc, int Nstore, long sA, long sB, long sC) {
  __shared__ __align__(16) char lds[32768];   // 2 slots x [A 8KB | B 8KB]
  const int tid = threadIdx.x;
  const int lane = tid & 63, wv = tid >> 6;
  const int lr = lane & 15, h16 = lane >> 4;

  const int tm = blockIdx.x, tn = blockIdx.y, bz = blockIdx.z;
  const bf16* A = Ag + (long)bz * sA + (long)tm * 128 * K;
  const bf16* B = Bg + (long)bz * sB + (long)tn * 128 * K;

  // staging: physical 16B-block delta -> logical beta = sigma(delta)
  int srcE[2], dstW[2];
#pragma unroll
  for (int j = 0; j < 2; ++j) {
    int d = j * 256 + tid;
    int b = d ^ ((d >> 3) & 3);
    srcE[j] = (b >> 2) * K + (b & 3) * 8;   // row*K + 8-elem col slot
    dstW[j] = (j * 256 + wv * 64) * 16;     // wave-uniform byte base (+lane*16 by HW)
  }
  const bf16* aS0 = A + srcE[0];
  const bf16* aS1 = A + srcE[1];
  const bf16* bS0 = B + srcE[0];
  const bf16* bS1 = B + srcE[1];
  auto STAGE = [&](int slot, int t) {
    int kOff = t * 32;
    gld_lds16(aS0 + kOff, lds + slot + dstW[0]);
    gld_lds16(aS1 + kOff, lds + slot + dstW[1]);
    gld_lds16(bS0 + kOff, lds + slot + 8192 + dstW[0]);
    gld_lds16(bS1 + kOff, lds + slot + 8192 + dstW[1]);
  };

  // swizzled ds_read byte offsets (constant per lane)
  const int wr = (wv >> 1) * 64, wc = (wv & 1) * 64;
  int aoff[4], boff[4];
#pragma unroll
  for (int m = 0; m < 4; ++m) {
    int La = (wr + m * 16 + lr) * 64 + h16 * 16;
    aoff[m] = La ^ (((La >> 7) & 3) << 4);
    int Lb = (wc + m * 16 + lr) * 64 + h16 * 16;
    boff[m] = 8192 + (Lb ^ (((Lb >> 7) & 3) << 4));
  }

  f32x4 acc[4][4] = {};
  short8 a[4], b[4];

  // prologue: tile0 -> slot0, landed before loop
  STAGE(0, 0);
  VMC0();
  BAR();

#pragma unroll 2
  for (int t = 0; t < NT; ++t) {
    const int cur = (t & 1) * 16384;
    if (t + 1 < NT) STAGE(16384 - cur, t + 1);   // other slot; its reads sealed @t-1
#pragma unroll
    for (int m = 0; m < 4; ++m) a[m] = *(const short8*)(lds + cur + aoff[m]);
#pragma unroll
    for (int n = 0; n < 4; ++n) b[n] = *(const short8*)(lds + cur + boff[n]);
    __builtin_amdgcn_s_setprio(1);
#pragma unroll
    for (int m = 0; m < 4; ++m)
#pragma unroll
      for (int n = 0; n < 4; ++n)
        acc[m][n] = __builtin_amdgcn_mfma_f32_16x16x32_bf16(a[m], b[n], acc[m][n], 0, 0, 0);
    __builtin_amdgcn_s_setprio(0);
    if (t + 1 < NT) VMC0();   // next tile landed (covered by ds_read+MFMA time)
    BAR();
  }

  if constexpr (sizeof(OUT_T) == 4) {
    // ---- wide-store epilogue: per-wave LDS transpose -> dwordx4 stores ----
    // (final loop BAR sealed all K-loop ds_reads; each wave touches only its
    //  own 8KB slice afterwards)
    float* Cf = (float*)Cg + (long)bz * sC;
    float bv[4];
#pragma unroll
    for (int n = 0; n < 4; ++n) {
      int col = tn * 128 + wc + lr + n * 16;
      bv[n] = (BIAS && col < Nstore) ? bias[col] : 0.f;
    }
    char* reg = lds + wv * 8192;        // 64 cols x 32 rows f32, col-major
    const int rowL = lane & 31, cb = lane >> 5;
#pragma unroll
    for (int mm = 0; mm < 2; ++mm) {
#pragma unroll
      for (int mp = 0; mp < 2; ++mp)
#pragma unroll
        for (int n = 0; n < 4; ++n) {
          f32x4 v = acc[mm * 2 + mp][n];
          v[0] += bv[n]; v[1] += bv[n]; v[2] += bv[n]; v[3] += bv[n];
          int col = lr + n * 16;
          int rho = mp * 16 + h16 * 4;
          int w = col * 32 + (rho ^ ((col & 7) << 2));
          *(f32x4*)(reg + w * 4) = v;
        }
      const long rowg = tm * 128 + wr + mm * 32 + rowL;
#pragma unroll
      for (int k = 0; k < 8; ++k) {
        f32x4 o;
#pragma unroll
        for (int c = 0; c < 4; ++c) {
          int col = k * 8 + cb * 4 + c;
          int w = col * 32 + (rowL ^ ((col & 7) << 2));
          o[c] = *(const float*)(reg + w * 4);
        }
        int gcol = tn * 128 + wc + k * 8 + cb * 4;
        float* dst = Cf + rowg * (long)ldc + gcol;
        if (gcol + 3 < Nstore) {
          if constexpr (NTS) __builtin_nontemporal_store(o, (f32x4*)dst);
          else               *(f32x4*)dst = o;
        } else {
#pragma unroll
          for (int c = 0; c < 4; ++c)
            if (gcol + c < Nstore) {
              if constexpr (NTS) __builtin_nontemporal_store(o[c], dst + c);
              else               dst[c] = o[c];
            }
        }
      }
    }
  } else {
    // ---- bf16 epilogue (small GEMMs; outputs are re-read -> keep cached) ----
    OUT_T* C = Cg + (long)bz * sC;
    const int crow0 = tm * 128 + wr + h16 * 4;
    const int ccol0 = tn * 128 + wc + lr;
#pragma unroll
    for (int m = 0; m < 4; ++m)
#pragma unroll
      for (int n = 0; n < 4; ++n) {
        int col = ccol0 + n * 16;
        if (col < Nstore) {
#pragma unroll
          for (int j = 0; j < 4; ++j) {
            long row = crow0 + m * 16 + j;
            C[row * ldc + col] = __float2bfloat16(acc[m][n][j]);
          }
        }
      }
  }
}

extern "C" void kernel_launch(void* const* d_in, const int* in_sizes, int n_in,
                              void* d_out, int out_size, void* d_ws, size_t ws_size,
                              hipStream_t stream) {
  const int*   idx     = (const int*)d_in[0];
  const float* w_embed = (const float*)d_in[1];
  const float* w_pos   = (const float*)d_in[2];
  const float* wq      = (const float*)d_in[3];
  const float* wk      = (const float*)d_in[4];
  const float* wv      = (const float*)d_in[5];
  const float* w_out   = (const float*)d_in[6];
  const float* b_out   = (const float*)d_in[7];
  float* out = (float*)d_out;

  size_t off = 0;
  auto alloc = [&](size_t bytes) {
    void* p = (char*)d_ws + off;
    off += (bytes + 255) & ~(size_t)255;
    return p;
  };
  bf16* x_bf    = (bf16*)alloc((size_t)MROWS * DIM * 2);
  bf16* wqkv_bf = (bf16*)alloc((size_t)3 * DIM * DIM * 2);
  bf16* wout_bf = (bf16*)alloc((size_t)VPAD * DIM * 2);
  bf16* qkv     = (bf16*)alloc((size_t)3 * MROWS * DIM * 2);
  bf16* vT      = (bf16*)alloc((size_t)NBATCH * DIM * SEQ * 2);
  float* scores = (float*)alloc((size_t)NBATCH * SEQ * SEQ * 4);
  bf16* P       = (bf16*)alloc((size_t)NBATCH * SEQ * SEQ * 2);
  bf16* attn    = (bf16*)alloc((size_t)MROWS * DIM * 2);

  const long QKV_S = (long)MROWS * DIM;
  const long W_S   = (long)DIM * DIM;

  // 1. embed
  embed_kernel<<<MROWS, 256, 0, stream>>>(idx, w_embed, w_pos, x_bf);

  // 2. weight converts (bf16; w_out zero-padded to VPAD rows)
  conv4_kernel<<<256, 256, 0, stream>>>(wq, wqkv_bf,           W_S, W_S);
  conv4_kernel<<<256, 256, 0, stream>>>(wk, wqkv_bf + W_S,     W_S, W_S);
  conv4_kernel<<<256, 256, 0, stream>>>(wv, wqkv_bf + 2 * W_S, W_S, W_S);
  conv4_kernel<<<2048, 256, 0, stream>>>(w_out, wout_bf, (long)VOCAB * DIM, (long)VPAD * DIM);

  // 3. q,k,v = x @ {wq,wk,wv}^T   (K=640 -> NT=20)
  gemm_pipe<20, bf16, false, false><<<dim3(MROWS / 128, DIM / 128, 3), 256, 0, stream>>>(
      x_bf, wqkv_bf, qkv, nullptr, DIM, DIM, DIM, 0, W_S, QKV_S);

  // 4. vT per batch
  {
    long n = (long)NBATCH * DIM * SEQ;
    transpose_v<<<(int)((n + 255) / 256), 256, 0, stream>>>(qkv + 2 * QKV_S, vT);
  }

  // 5. scores[b] = q[b] @ k[b]^T  (K=640 -> NT=20; re-read by softmax -> cached)
  gemm_pipe<20, float, false, false><<<dim3(SEQ / 128, SEQ / 128, NBATCH), 256, 0, stream>>>(
      qkv, qkv + QKV_S, scores, nullptr, DIM, SEQ, SEQ,
      (long)SEQ * DIM, (long)SEQ * DIM, (long)SEQ * SEQ);

  // 6. causal softmax -> P bf16
  softmax_kernel<<<MROWS / 4, 256, 0, stream>>>(scores, P);

  // 7. attn[b] = P[b] @ vT[b]^T  (K=256 -> NT=8)
  gemm_pipe<8, bf16, false, false><<<dim3(SEQ / 128, DIM / 128, NBATCH), 256, 0, stream>>>(
      P, vT, attn, nullptr, SEQ, DIM, DIM,
      (long)SEQ * SEQ, (long)DIM * SEQ, (long)SEQ * DIM);

  // 8. logits = attn @ w_out^T + b_out  (non-temporal C stores)
  gemm_pipe<20, float, true, true><<<dim3(MROWS / 128, VPAD / 128, 1), 256, 0, stream>>>(
      attn, wout_bf, out, b_out, DIM, VOCAB, VOCAB, 0, 0, 0);
}

// Round 8
// 1172.478 us; speedup vs baseline: 1.4318x; 1.4318x over previous
//
#include <hip/hip_runtime.h>
#include <hip/hip_bf16.h>
#include <stdint.h>

#define VOCAB 50257
#define VPAD  50432   /* 788*64 = 394*128 */
#define DIM   640
#define SEQ   256
#define NBATCH 16
#define MROWS 4096    /* NBATCH*SEQ */

using bf16 = __hip_bfloat16;
typedef __attribute__((ext_vector_type(8))) short short8;
typedef __attribute__((ext_vector_type(4))) float f32x4;
struct bf16x4 { bf16 a, b, c, d; };

__device__ __forceinline__ void gld_lds16(const void* g, void* l) {
  __builtin_amdgcn_global_load_lds(
      (const __attribute__((address_space(1))) void*)g,
      (__attribute__((address_space(3))) void*)l, 16, 0, 0);
}

#define BAR() asm volatile("s_barrier" ::: "memory")
#define VMC0() asm volatile("s_waitcnt vmcnt(0)" ::: "memory")

// ---------------- embed: x = w_embed[idx] + w_pos  -> bf16 ----------------
__global__ void embed_kernel(const int* __restrict__ idx,
                             const float* __restrict__ we,
                             const float* __restrict__ wp,
                             bf16* __restrict__ xb) {
  int row = blockIdx.x;
  int t = row & (SEQ - 1);
  int tok = idx[row];
  const float* src = we + (long)tok * DIM;
  const float* pos = wp + (long)t * DIM;
  for (int d = threadIdx.x * 4; d < DIM; d += blockDim.x * 4) {
    float4 s = *(const float4*)(src + d);
    float4 p = *(const float4*)(pos + d);
    bf16x4 o = { __float2bfloat16(s.x + p.x), __float2bfloat16(s.y + p.y),
                 __float2bfloat16(s.z + p.z), __float2bfloat16(s.w + p.w) };
    *(bf16x4*)(xb + (long)row * DIM + d) = o;
  }
}

// ---------------- f32 -> bf16 convert (x4) with zero tail pad ----------------
__global__ void conv4_kernel(const float* __restrict__ src, bf16* __restrict__ dst,
                             long n_src, long n_dst) {
  long i = ((long)blockIdx.x * blockDim.x + threadIdx.x) * 4;
  long stride = (long)gridDim.x * blockDim.x * 4;
  for (; i < n_dst; i += stride) {
    float4 v = (i < n_src) ? *(const float4*)(src + i) : make_float4(0.f, 0.f, 0.f, 0.f);
    bf16x4 o = { __float2bfloat16(v.x), __float2bfloat16(v.y),
                 __float2bfloat16(v.z), __float2bfloat16(v.w) };
    *(bf16x4*)(dst + i) = o;
  }
}

// ---------------- v (16*256,640) -> vT (16,640,256) ----------------
__global__ void transpose_v(const bf16* __restrict__ v, bf16* __restrict__ vt) {
  long i = (long)blockIdx.x * blockDim.x + threadIdx.x;
  if (i >= (long)NBATCH * DIM * SEQ) return;
  int t = (int)(i & (SEQ - 1));
  long be = i >> 8;
  int e = (int)(be % DIM);
  int b = (int)(be / DIM);
  vt[i] = v[((long)b * SEQ + t) * DIM + e];
}

// ---------------- causal softmax: scores f32 -> P bf16 ----------------
__global__ void softmax_kernel(const float* __restrict__ sc, bf16* __restrict__ p) {
  int wid = threadIdx.x >> 6, lane = threadIdx.x & 63;
  int row = blockIdx.x * 4 + wid;
  int t = row & (SEQ - 1);
  const float* srow = sc + (long)row * SEQ;
  const float rsc = 0.03952847075210474f;  // 1/sqrt(640)
  float v[4];
  float mx = -1e30f;
#pragma unroll
  for (int i = 0; i < 4; ++i) {
    int s = lane + 64 * i;
    v[i] = (s <= t) ? srow[s] * rsc : -1e30f;
    mx = fmaxf(mx, v[i]);
  }
#pragma unroll
  for (int off = 32; off; off >>= 1) mx = fmaxf(mx, __shfl_xor(mx, off, 64));
  float sum = 0.f;
#pragma unroll
  for (int i = 0; i < 4; ++i) {
    int s = lane + 64 * i;
    v[i] = (s <= t) ? __expf(v[i] - mx) : 0.f;
    sum += v[i];
  }
#pragma unroll
  for (int off = 32; off; off >>= 1) sum += __shfl_xor(sum, off, 64);
  float inv = 1.f / sum;
#pragma unroll
  for (int i = 0; i < 4; ++i)
    p[(long)row * SEQ + lane + 64 * i] = __float2bfloat16(v[i] * inv);
}

// ========= 128x128 GEMM, 2-slot depth-1 pipeline (r5 config, small GEMMs) =========
template <int NT, typename OUT_T, bool BIAS>
__global__ __launch_bounds__(256, 4) void gemm_pipe(
    const bf16* __restrict__ Ag, const bf16* __restrict__ Bg,
    OUT_T* __restrict__ Cg, const float* __restrict__ bias,
    int K, int ldc, int Nstore, long sA, long sB, long sC) {
  __shared__ __align__(16) char lds[32768];   // 2 slots x [A 8KB | B 8KB]
  const int tid = threadIdx.x;
  const int lane = tid & 63, wv = tid >> 6;
  const int lr = lane & 15, h16 = lane >> 4;

  const int tm = blockIdx.x, tn = blockIdx.y, bz = blockIdx.z;
  const bf16* A = Ag + (long)bz * sA + (long)tm * 128 * K;
  const bf16* B = Bg + (long)bz * sB + (long)tn * 128 * K;

  int srcE[2], dstW[2];
#pragma unroll
  for (int j = 0; j < 2; ++j) {
    int d = j * 256 + tid;
    int b = d ^ ((d >> 3) & 3);
    srcE[j] = (b >> 2) * K + (b & 3) * 8;
    dstW[j] = (j * 256 + wv * 64) * 16;
  }
  const bf16* aS0 = A + srcE[0];
  const bf16* aS1 = A + srcE[1];
  const bf16* bS0 = B + srcE[0];
  const bf16* bS1 = B + srcE[1];
  auto STAGE = [&](int slot, int t) {
    int kOff = t * 32;
    gld_lds16(aS0 + kOff, lds + slot + dstW[0]);
    gld_lds16(aS1 + kOff, lds + slot + dstW[1]);
    gld_lds16(bS0 + kOff, lds + slot + 8192 + dstW[0]);
    gld_lds16(bS1 + kOff, lds + slot + 8192 + dstW[1]);
  };

  const int wr = (wv >> 1) * 64, wc = (wv & 1) * 64;
  int aoff[4], boff[4];
#pragma unroll
  for (int m = 0; m < 4; ++m) {
    int La = (wr + m * 16 + lr) * 64 + h16 * 16;
    aoff[m] = La ^ (((La >> 7) & 3) << 4);
    int Lb = (wc + m * 16 + lr) * 64 + h16 * 16;
    boff[m] = 8192 + (Lb ^ (((Lb >> 7) & 3) << 4));
  }

  f32x4 acc[4][4] = {};
  short8 a[4], b[4];

  STAGE(0, 0);
  VMC0();
  BAR();

#pragma unroll 2
  for (int t = 0; t < NT; ++t) {
    const int cur = (t & 1) * 16384;
    if (t + 1 < NT) STAGE(16384 - cur, t + 1);
#pragma unroll
    for (int m = 0; m < 4; ++m) a[m] = *(const short8*)(lds + cur + aoff[m]);
#pragma unroll
    for (int n = 0; n < 4; ++n) b[n] = *(const short8*)(lds + cur + boff[n]);
    __builtin_amdgcn_s_setprio(1);
#pragma unroll
    for (int m = 0; m < 4; ++m)
#pragma unroll
      for (int n = 0; n < 4; ++n)
        acc[m][n] = __builtin_amdgcn_mfma_f32_16x16x32_bf16(a[m], b[n], acc[m][n], 0, 0, 0);
    __builtin_amdgcn_s_setprio(0);
    if (t + 1 < NT) VMC0();
    BAR();
  }

  if constexpr (sizeof(OUT_T) == 4) {
    // wide-store epilogue via per-wave LDS transpose (cached stores)
    float* Cf = (float*)Cg + (long)bz * sC;
    float bv[4];
#pragma unroll
    for (int n = 0; n < 4; ++n) {
      int col = tn * 128 + wc + lr + n * 16;
      bv[n] = (BIAS && col < Nstore) ? bias[col] : 0.f;
    }
    char* reg = lds + wv * 8192;
    const int rowL = lane & 31, cb = lane >> 5;
#pragma unroll
    for (int mm = 0; mm < 2; ++mm) {
#pragma unroll
      for (int mp = 0; mp < 2; ++mp)
#pragma unroll
        for (int n = 0; n < 4; ++n) {
          f32x4 v = acc[mm * 2 + mp][n];
          v[0] += bv[n]; v[1] += bv[n]; v[2] += bv[n]; v[3] += bv[n];
          int col = lr + n * 16;
          int rho = mp * 16 + h16 * 4;
          int w = col * 32 + (rho ^ ((col & 7) << 2));
          *(f32x4*)(reg + w * 4) = v;
        }
      const long rowg = tm * 128 + wr + mm * 32 + rowL;
#pragma unroll
      for (int k = 0; k < 8; ++k) {
        f32x4 o;
#pragma unroll
        for (int c = 0; c < 4; ++c) {
          int col = k * 8 + cb * 4 + c;
          int w = col * 32 + (rowL ^ ((col & 7) << 2));
          o[c] = *(const float*)(reg + w * 4);
        }
        int gcol = tn * 128 + wc + k * 8 + cb * 4;
        float* dst = Cf + rowg * (long)ldc + gcol;
        if (gcol + 3 < Nstore) {
          *(f32x4*)dst = o;
        } else {
#pragma unroll
          for (int c = 0; c < 4; ++c)
            if (gcol + c < Nstore) dst[c] = o[c];
        }
      }
    }
  } else {
    OUT_T* C = Cg + (long)bz * sC;
    const int crow0 = tm * 128 + wr + h16 * 4;
    const int ccol0 = tn * 128 + wc + lr;
#pragma unroll
    for (int m = 0; m < 4; ++m)
#pragma unroll
      for (int n = 0; n < 4; ++n) {
        int col = ccol0 + n * 16;
        if (col < Nstore) {
#pragma unroll
          for (int j = 0; j < 4; ++j) {
            long row = crow0 + m * 16 + j;
            C[row * ldc + col] = __float2bfloat16(acc[m][n][j]);
          }
        }
      }
  }
}

// ========= logits GEMM: barrier-free, LDS-free, register-direct =========
// C = A * B^T + bias. A:(4096,640) bf16, B:(50432,640) bf16 zero-padded,
// C:(4096,VOCAB) f32. Each WAVE independently computes a 64x64 C tile:
// MFMA fragments loaded global->VGPR (dwordx4, 16 full 64B lines per load =
// layout minimum), double-buffered 1 K-tile ahead. No __shared__, no barrier,
// no shared vmcnt -> no convoy: a wave stalls only on its own loads; 12
// independent waves/CU decorrelate (r1-r6 showed the block-wide vmcnt(0)+
// barrier convoy pins MfmaUtil at ~23% regardless of prefetch depth).
// Block's 4 waves = consecutive tm at same tn -> B-frag loads L1-hit 4-way.
__global__ __launch_bounds__(256, 3) void gemm_wave(
    const bf16* __restrict__ Ag, const bf16* __restrict__ Bg,
    float* __restrict__ Cg, const float* __restrict__ bias) {
  const int lane = threadIdx.x & 63, wv = threadIdx.x >> 6;
  const int w = blockIdx.x * 4 + wv;
  const int tm = w & 63, tn = w >> 6;        // tm fastest (A tiny/L2; B panel shared)
  const int lr = lane & 15, kh = lane >> 4;

  // frag addressing: row = tile*64 + frag*16 + lr ; k-chunk = kh*8 elems + t*32
  const bf16* pA = Ag + (long)(tm * 64 + lr) * DIM + kh * 8;
  const bf16* pB = Bg + (long)(tn * 64 + lr) * DIM + kh * 8;

  f32x4 acc[4][4] = {};
  short8 A0[4], B0[4], A1[4], B1[4];

#define LD(BA, BB, T)                                                         \
  { _Pragma("unroll") for (int m = 0; m < 4; ++m)                             \
      BA[m] = *(const short8*)(pA + m * (16 * DIM) + (T) * 32);               \
    _Pragma("unroll") for (int n = 0; n < 4; ++n)                             \
      BB[n] = *(const short8*)(pB + n * (16 * DIM) + (T) * 32); }
#define FM(BA, BB)                                                            \
  { _Pragma("unroll") for (int m = 0; m < 4; ++m)                             \
    _Pragma("unroll") for (int n = 0; n < 4; ++n)                             \
      acc[m][n] = __builtin_amdgcn_mfma_f32_16x16x32_bf16(                    \
          BA[m], BB[n], acc[m][n], 0, 0, 0); }

  LD(A0, B0, 0);
#pragma unroll
  for (int t = 0; t < 20; t += 2) {
    if (t + 1 < 20) LD(A1, B1, t + 1);   // issue next while computing cur
    FM(A0, B0);
    if (t + 2 < 20) LD(A0, B0, t + 2);
    if (t + 1 < 20) FM(A1, B1);
  }
#undef LD
#undef FM

  // epilogue: C layout row=(lane>>4)*4+j, col=lane&15 (verified m89/m91)
  const int crow0 = tm * 64 + kh * 4;
  const int ccol0 = tn * 64 + lr;
#pragma unroll
  for (int m = 0; m < 4; ++m)
#pragma unroll
    for (int n = 0; n < 4; ++n) {
      int col = ccol0 + n * 16;
      if (col < VOCAB) {
        float bv = bias[col];
#pragma unroll
        for (int j = 0; j < 4; ++j)
          Cg[(long)(crow0 + m * 16 + j) * VOCAB + col] = acc[m][n][j] + bv;
      }
    }
}

extern "C" void kernel_launch(void* const* d_in, const int* in_sizes, int n_in,
                              void* d_out, int out_size, void* d_ws, size_t ws_size,
                              hipStream_t stream) {
  const int*   idx     = (const int*)d_in[0];
  const float* w_embed = (const float*)d_in[1];
  const float* w_pos   = (const float*)d_in[2];
  const float* wq      = (const float*)d_in[3];
  const float* wk      = (const float*)d_in[4];
  const float* wv      = (const float*)d_in[5];
  const float* w_out   = (const float*)d_in[6];
  const float* b_out   = (const float*)d_in[7];
  float* out = (float*)d_out;

  size_t off = 0;
  auto alloc = [&](size_t bytes) {
    void* p = (char*)d_ws + off;
    off += (bytes + 255) & ~(size_t)255;
    return p;
  };
  bf16* x_bf    = (bf16*)alloc((size_t)MROWS * DIM * 2);
  bf16* wqkv_bf = (bf16*)alloc((size_t)3 * DIM * DIM * 2);
  bf16* wout_bf = (bf16*)alloc((size_t)VPAD * DIM * 2);
  bf16* qkv     = (bf16*)alloc((size_t)3 * MROWS * DIM * 2);
  bf16* vT      = (bf16*)alloc((size_t)NBATCH * DIM * SEQ * 2);
  float* scores = (float*)alloc((size_t)NBATCH * SEQ * SEQ * 4);
  bf16* P       = (bf16*)alloc((size_t)NBATCH * SEQ * SEQ * 2);
  bf16* attn    = (bf16*)alloc((size_t)MROWS * DIM * 2);

  const long QKV_S = (long)MROWS * DIM;
  const long W_S   = (long)DIM * DIM;

  // 1. embed
  embed_kernel<<<MROWS, 256, 0, stream>>>(idx, w_embed, w_pos, x_bf);

  // 2. weight converts (bf16; w_out zero-padded to VPAD rows)
  conv4_kernel<<<256, 256, 0, stream>>>(wq, wqkv_bf,           W_S, W_S);
  conv4_kernel<<<256, 256, 0, stream>>>(wk, wqkv_bf + W_S,     W_S, W_S);
  conv4_kernel<<<256, 256, 0, stream>>>(wv, wqkv_bf + 2 * W_S, W_S, W_S);
  conv4_kernel<<<2048, 256, 0, stream>>>(w_out, wout_bf, (long)VOCAB * DIM, (long)VPAD * DIM);

  // 3. q,k,v = x @ {wq,wk,wv}^T   (K=640 -> NT=20)
  gemm_pipe<20, bf16, false><<<dim3(MROWS / 128, DIM / 128, 3), 256, 0, stream>>>(
      x_bf, wqkv_bf, qkv, nullptr, DIM, DIM, DIM, 0, W_S, QKV_S);

  // 4. vT per batch
  {
    long n = (long)NBATCH * DIM * SEQ;
    transpose_v<<<(int)((n + 255) / 256), 256, 0, stream>>>(qkv + 2 * QKV_S, vT);
  }

  // 5. scores[b] = q[b] @ k[b]^T  (K=640 -> NT=20)
  gemm_pipe<20, float, false><<<dim3(SEQ / 128, SEQ / 128, NBATCH), 256, 0, stream>>>(
      qkv, qkv + QKV_S, scores, nullptr, DIM, SEQ, SEQ,
      (long)SEQ * DIM, (long)SEQ * DIM, (long)SEQ * SEQ);

  // 6. causal softmax -> P bf16
  softmax_kernel<<<MROWS / 4, 256, 0, stream>>>(scores, P);

  // 7. attn[b] = P[b] @ vT[b]^T  (K=256 -> NT=8)
  gemm_pipe<8, bf16, false><<<dim3(SEQ / 128, DIM / 128, NBATCH), 256, 0, stream>>>(
      P, vT, attn, nullptr, SEQ, DIM, DIM,
      (long)SEQ * SEQ, (long)DIM * SEQ, (long)SEQ * DIM);

  // 8. logits = attn @ w_out^T + b_out  (wave-independent register-direct)
  gemm_wave<<<(64 * 788) / 4, 256, 0, stream>>>(attn, wout_bf, out, b_out);
}

// Round 9
// 604.820 us; speedup vs baseline: 2.7756x; 1.9386x over previous
//
#include <hip/hip_runtime.h>
#include <hip/hip_bf16.h>
#include <stdint.h>

#define VOCAB 50257
#define VPAD  50432   /* 394*128 */
#define DIM   640
#define SEQ   256
#define NBATCH 16
#define MROWS 4096    /* NBATCH*SEQ */

using bf16 = __hip_bfloat16;
typedef __attribute__((ext_vector_type(8))) short short8;
typedef __attribute__((ext_vector_type(4))) float f32x4;
struct bf16x4 { bf16 a, b, c, d; };

__device__ __forceinline__ void gld_lds16(const void* g, void* l) {
  __builtin_amdgcn_global_load_lds(
      (const __attribute__((address_space(1))) void*)g,
      (__attribute__((address_space(3))) void*)l, 16, 0, 0);
}

#define BAR() asm volatile("s_barrier" ::: "memory")
#define VMC0() asm volatile("s_waitcnt vmcnt(0)" ::: "memory")

// ---------------- embed: x = w_embed[idx] + w_pos  -> bf16 ----------------
__global__ void embed_kernel(const int* __restrict__ idx,
                             const float* __restrict__ we,
                             const float* __restrict__ wp,
                             bf16* __restrict__ xb) {
  int row = blockIdx.x;
  int t = row & (SEQ - 1);
  int tok = idx[row];
  const float* src = we + (long)tok * DIM;
  const float* pos = wp + (long)t * DIM;
  for (int d = threadIdx.x * 4; d < DIM; d += blockDim.x * 4) {
    float4 s = *(const float4*)(src + d);
    float4 p = *(const float4*)(pos + d);
    bf16x4 o = { __float2bfloat16(s.x + p.x), __float2bfloat16(s.y + p.y),
                 __float2bfloat16(s.z + p.z), __float2bfloat16(s.w + p.w) };
    *(bf16x4*)(xb + (long)row * DIM + d) = o;
  }
}

// ---------------- f32 -> bf16 convert (x4) with zero tail pad ----------------
__global__ void conv4_kernel(const float* __restrict__ src, bf16* __restrict__ dst,
                             long n_src, long n_dst) {
  long i = ((long)blockIdx.x * blockDim.x + threadIdx.x) * 4;
  long stride = (long)gridDim.x * blockDim.x * 4;
  for (; i < n_dst; i += stride) {
    float4 v = (i < n_src) ? *(const float4*)(src + i) : make_float4(0.f, 0.f, 0.f, 0.f);
    bf16x4 o = { __float2bfloat16(v.x), __float2bfloat16(v.y),
                 __float2bfloat16(v.z), __float2bfloat16(v.w) };
    *(bf16x4*)(dst + i) = o;
  }
}

// ---------------- v (16*256,640) -> vT (16,640,256) ----------------
__global__ void transpose_v(const bf16* __restrict__ v, bf16* __restrict__ vt) {
  long i = (long)blockIdx.x * blockDim.x + threadIdx.x;
  if (i >= (long)NBATCH * DIM * SEQ) return;
  int t = (int)(i & (SEQ - 1));
  long be = i >> 8;
  int e = (int)(be % DIM);
  int b = (int)(be / DIM);
  vt[i] = v[((long)b * SEQ + t) * DIM + e];
}

// ---------------- causal softmax: scores f32 -> P bf16 ----------------
__global__ void softmax_kernel(const float* __restrict__ sc, bf16* __restrict__ p) {
  int wid = threadIdx.x >> 6, lane = threadIdx.x & 63;
  int row = blockIdx.x * 4 + wid;
  int t = row & (SEQ - 1);
  const float* srow = sc + (long)row * SEQ;
  const float rsc = 0.03952847075210474f;  // 1/sqrt(640)
  float v[4];
  float mx = -1e30f;
#pragma unroll
  for (int i = 0; i < 4; ++i) {
    int s = lane + 64 * i;
    v[i] = (s <= t) ? srow[s] * rsc : -1e30f;
    mx = fmaxf(mx, v[i]);
  }
#pragma unroll
  for (int off = 32; off; off >>= 1) mx = fmaxf(mx, __shfl_xor(mx, off, 64));
  float sum = 0.f;
#pragma unroll
  for (int i = 0; i < 4; ++i) {
    int s = lane + 64 * i;
    v[i] = (s <= t) ? __expf(v[i] - mx) : 0.f;
    sum += v[i];
  }
#pragma unroll
  for (int off = 32; off; off >>= 1) sum += __shfl_xor(sum, off, 64);
  float inv = 1.f / sum;
#pragma unroll
  for (int i = 0; i < 4; ++i)
    p[(long)row * SEQ + lane + 64 * i] = __float2bfloat16(v[i] * inv);
}

// ========= 128x128 GEMM, 2-slot depth-1 pipeline (r5 config, small GEMMs) =========
template <int NT, typename OUT_T, bool BIAS>
__global__ __launch_bounds__(256, 4) void gemm_pipe(
    const bf16* __restrict__ Ag, const bf16* __restrict__ Bg,
    OUT_T* __restrict__ Cg, const float* __restrict__ bias,
    int K, int ldc, int Nstore, long sA, long sB, long sC) {
  __shared__ __align__(16) char lds[32768];   // 2 slots x [A 8KB | B 8KB]
  const int tid = threadIdx.x;
  const int lane = tid & 63, wv = tid >> 6;
  const int lr = lane & 15, h16 = lane >> 4;

  const int tm = blockIdx.x, tn = blockIdx.y, bz = blockIdx.z;
  const bf16* A = Ag + (long)bz * sA + (long)tm * 128 * K;
  const bf16* B = Bg + (long)bz * sB + (long)tn * 128 * K;

  int srcE[2], dstW[2];
#pragma unroll
  for (int j = 0; j < 2; ++j) {
    int d = j * 256 + tid;
    int b = d ^ ((d >> 3) & 3);
    srcE[j] = (b >> 2) * K + (b & 3) * 8;
    dstW[j] = (j * 256 + wv * 64) * 16;
  }
  const bf16* aS0 = A + srcE[0];
  const bf16* aS1 = A + srcE[1];
  const bf16* bS0 = B + srcE[0];
  const bf16* bS1 = B + srcE[1];
  auto STAGE = [&](int slot, int t) {
    int kOff = t * 32;
    gld_lds16(aS0 + kOff, lds + slot + dstW[0]);
    gld_lds16(aS1 + kOff, lds + slot + dstW[1]);
    gld_lds16(bS0 + kOff, lds + slot + 8192 + dstW[0]);
    gld_lds16(bS1 + kOff, lds + slot + 8192 + dstW[1]);
  };

  const int wr = (wv >> 1) * 64, wc = (wv & 1) * 64;
  int aoff[4], boff[4];
#pragma unroll
  for (int m = 0; m < 4; ++m) {
    int La = (wr + m * 16 + lr) * 64 + h16 * 16;
    aoff[m] = La ^ (((La >> 7) & 3) << 4);
    int Lb = (wc + m * 16 + lr) * 64 + h16 * 16;
    boff[m] = 8192 + (Lb ^ (((Lb >> 7) & 3) << 4));
  }

  f32x4 acc[4][4] = {};
  short8 a[4], b[4];

  STAGE(0, 0);
  VMC0();
  BAR();

#pragma unroll 2
  for (int t = 0; t < NT; ++t) {
    const int cur = (t & 1) * 16384;
    if (t + 1 < NT) STAGE(16384 - cur, t + 1);
#pragma unroll
    for (int m = 0; m < 4; ++m) a[m] = *(const short8*)(lds + cur + aoff[m]);
#pragma unroll
    for (int n = 0; n < 4; ++n) b[n] = *(const short8*)(lds + cur + boff[n]);
    __builtin_amdgcn_s_setprio(1);
#pragma unroll
    for (int m = 0; m < 4; ++m)
#pragma unroll
      for (int n = 0; n < 4; ++n)
        acc[m][n] = __builtin_amdgcn_mfma_f32_16x16x32_bf16(a[m], b[n], acc[m][n], 0, 0, 0);
    __builtin_amdgcn_s_setprio(0);
    if (t + 1 < NT) VMC0();
    BAR();
  }

  if constexpr (sizeof(OUT_T) == 4) {
    // wide-store epilogue via per-wave LDS transpose (cached stores)
    float* Cf = (float*)Cg + (long)bz * sC;
    float bv[4];
#pragma unroll
    for (int n = 0; n < 4; ++n) {
      int col = tn * 128 + wc + lr + n * 16;
      bv[n] = (BIAS && col < Nstore) ? bias[col] : 0.f;
    }
    char* reg = lds + wv * 8192;
    const int rowL = lane & 31, cb = lane >> 5;
#pragma unroll
    for (int mm = 0; mm < 2; ++mm) {
#pragma unroll
      for (int mp = 0; mp < 2; ++mp)
#pragma unroll
        for (int n = 0; n < 4; ++n) {
          f32x4 v = acc[mm * 2 + mp][n];
          v[0] += bv[n]; v[1] += bv[n]; v[2] += bv[n]; v[3] += bv[n];
          int col = lr + n * 16;
          int rho = mp * 16 + h16 * 4;
          int w = col * 32 + (rho ^ ((col & 7) << 2));
          *(f32x4*)(reg + w * 4) = v;
        }
      const long rowg = tm * 128 + wr + mm * 32 + rowL;
#pragma unroll
      for (int k = 0; k < 8; ++k) {
        f32x4 o;
#pragma unroll
        for (int c = 0; c < 4; ++c) {
          int col = k * 8 + cb * 4 + c;
          int w = col * 32 + (rowL ^ ((col & 7) << 2));
          o[c] = *(const float*)(reg + w * 4);
        }
        int gcol = tn * 128 + wc + k * 8 + cb * 4;
        float* dst = Cf + rowg * (long)ldc + gcol;
        if (gcol + 3 < Nstore) {
          *(f32x4*)dst = o;
        } else {
#pragma unroll
          for (int c = 0; c < 4; ++c)
            if (gcol + c < Nstore) dst[c] = o[c];
        }
      }
    }
  } else {
    OUT_T* C = Cg + (long)bz * sC;
    const int crow0 = tm * 128 + wr + h16 * 4;
    const int ccol0 = tn * 128 + wc + lr;
#pragma unroll
    for (int m = 0; m < 4; ++m)
#pragma unroll
      for (int n = 0; n < 4; ++n) {
        int col = ccol0 + n * 16;
        if (col < Nstore) {
#pragma unroll
          for (int j = 0; j < 4; ++j) {
            long row = crow0 + m * 16 + j;
            C[row * ldc + col] = __float2bfloat16(acc[m][n][j]);
          }
        }
      }
  }
}

// ========= logits GEMM: 128x128 tile, 8 waves, HIGH-OCCUPANCY variant =========
// Same block tile / staging bytes / depth-1 schedule as gemm_pipe, but the
// tile is split over 8 waves (2M x 4N, 64x32 each): acc[4][2]=32 regs/wave,
// ~80 regs total -> ~6 waves/SIMD = 24 waves/CU (vs 16-wave cap of the
// 64x64/wave layout). Pure TLP experiment: r8 falsified the barrier-convoy
// theory (barrier-free was worse), leaving exposed memory latency x
// insufficient resident waves as the model; this raises waves 1.65x with
// everything else held fixed.
__global__ __launch_bounds__(512, 6) void gemm8(
    const bf16* __restrict__ Ag, const bf16* __restrict__ Bg,
    float* __restrict__ Cg, const float* __restrict__ bias) {
  __shared__ __align__(16) char lds[32768];   // 2 slots x [A 8KB | B 8KB]
  const int tid = threadIdx.x;
  const int lane = tid & 63, wv = tid >> 6;
  const int lr = lane & 15, h16 = lane >> 4;

  const int tm = blockIdx.x, tn = blockIdx.y;
  const bf16* A = Ag + (long)tm * 128 * DIM;
  const bf16* B = Bg + (long)tn * 128 * DIM;

  // staging: 512 threads, 1 A-load + 1 B-load each (16B), swizzled source
  int srcE, dstW;
  {
    int d = tid;                      // 16B-block index within 8KB half
    int b = d ^ ((d >> 3) & 3);
    srcE = (b >> 2) * DIM + (b & 3) * 8;
    dstW = (wv * 64) * 16;            // wave-uniform byte base (+lane*16 by HW)
  }
  const bf16* aS = A + srcE;
  const bf16* bS = B + srcE;
  auto STAGE = [&](int slot, int t) {
    int kOff = t * 32;
    gld_lds16(aS + kOff, lds + slot + dstW);
    gld_lds16(bS + kOff, lds + slot + 8192 + dstW);
  };

  // wave -> 64x32 output sub-tile
  const int wr = (wv >> 2) * 64, wc = (wv & 3) * 32;
  int aoff[4], boff[2];
#pragma unroll
  for (int m = 0; m < 4; ++m) {
    int La = (wr + m * 16 + lr) * 64 + h16 * 16;
    aoff[m] = La ^ (((La >> 7) & 3) << 4);
  }
#pragma unroll
  for (int n = 0; n < 2; ++n) {
    int Lb = (wc + n * 16 + lr) * 64 + h16 * 16;
    boff[n] = 8192 + (Lb ^ (((Lb >> 7) & 3) << 4));
  }

  f32x4 acc[4][2] = {};
  short8 a[4], b[2];

  STAGE(0, 0);
  VMC0();
  BAR();

#pragma unroll 2
  for (int t = 0; t < 20; ++t) {
    const int cur = (t & 1) * 16384;
    if (t + 1 < 20) STAGE(16384 - cur, t + 1);
#pragma unroll
    for (int m = 0; m < 4; ++m) a[m] = *(const short8*)(lds + cur + aoff[m]);
#pragma unroll
    for (int n = 0; n < 2; ++n) b[n] = *(const short8*)(lds + cur + boff[n]);
    __builtin_amdgcn_s_setprio(1);
#pragma unroll
    for (int m = 0; m < 4; ++m)
#pragma unroll
      for (int n = 0; n < 2; ++n)
        acc[m][n] = __builtin_amdgcn_mfma_f32_16x16x32_bf16(a[m], b[n], acc[m][n], 0, 0, 0);
    __builtin_amdgcn_s_setprio(0);
    if (t + 1 < 20) VMC0();
    BAR();
  }

  // epilogue: direct stores (C layout row=(lane>>4)*4+j, col=lane&15)
  const int crow0 = tm * 128 + wr + h16 * 4;
  const int ccol0 = tn * 128 + wc + lr;
  float bv[2];
#pragma unroll
  for (int n = 0; n < 2; ++n) {
    int col = ccol0 + n * 16;
    bv[n] = (col < VOCAB) ? bias[col] : 0.f;
  }
#pragma unroll
  for (int m = 0; m < 4; ++m)
#pragma unroll
    for (int n = 0; n < 2; ++n) {
      int col = ccol0 + n * 16;
      if (col < VOCAB) {
#pragma unroll
        for (int j = 0; j < 4; ++j)
          Cg[(long)(crow0 + m * 16 + j) * VOCAB + col] = acc[m][n][j] + bv[n];
      }
    }
}

extern "C" void kernel_launch(void* const* d_in, const int* in_sizes, int n_in,
                              void* d_out, int out_size, void* d_ws, size_t ws_size,
                              hipStream_t stream) {
  const int*   idx     = (const int*)d_in[0];
  const float* w_embed = (const float*)d_in[1];
  const float* w_pos   = (const float*)d_in[2];
  const float* wq      = (const float*)d_in[3];
  const float* wk      = (const float*)d_in[4];
  const float* wv      = (const float*)d_in[5];
  const float* w_out   = (const float*)d_in[6];
  const float* b_out   = (const float*)d_in[7];
  float* out = (float*)d_out;

  size_t off = 0;
  auto alloc = [&](size_t bytes) {
    void* p = (char*)d_ws + off;
    off += (bytes + 255) & ~(size_t)255;
    return p;
  };
  bf16* x_bf    = (bf16*)alloc((size_t)MROWS * DIM * 2);
  bf16* wqkv_bf = (bf16*)alloc((size_t)3 * DIM * DIM * 2);
  bf16* wout_bf = (bf16*)alloc((size_t)VPAD * DIM * 2);
  bf16* qkv     = (bf16*)alloc((size_t)3 * MROWS * DIM * 2);
  bf16* vT      = (bf16*)alloc((size_t)NBATCH * DIM * SEQ * 2);
  float* scores = (float*)alloc((size_t)NBATCH * SEQ * SEQ * 4);
  bf16* P       = (bf16*)alloc((size_t)NBATCH * SEQ * SEQ * 2);
  bf16* attn    = (bf16*)alloc((size_t)MROWS * DIM * 2);

  const long QKV_S = (long)MROWS * DIM;
  const long W_S   = (long)DIM * DIM;

  // 1. embed
  embed_kernel<<<MROWS, 256, 0, stream>>>(idx, w_embed, w_pos, x_bf);

  // 2. weight converts (bf16; w_out zero-padded to VPAD rows)
  conv4_kernel<<<256, 256, 0, stream>>>(wq, wqkv_bf,           W_S, W_S);
  conv4_kernel<<<256, 256, 0, stream>>>(wk, wqkv_bf + W_S,     W_S, W_S);
  conv4_kernel<<<256, 256, 0, stream>>>(wv, wqkv_bf + 2 * W_S, W_S, W_S);
  conv4_kernel<<<2048, 256, 0, stream>>>(w_out, wout_bf, (long)VOCAB * DIM, (long)VPAD * DIM);

  // 3. q,k,v = x @ {wq,wk,wv}^T   (K=640 -> NT=20)
  gemm_pipe<20, bf16, false><<<dim3(MROWS / 128, DIM / 128, 3), 256, 0, stream>>>(
      x_bf, wqkv_bf, qkv, nullptr, DIM, DIM, DIM, 0, W_S, QKV_S);

  // 4. vT per batch
  {
    long n = (long)NBATCH * DIM * SEQ;
    transpose_v<<<(int)((n + 255) / 256), 256, 0, stream>>>(qkv + 2 * QKV_S, vT);
  }

  // 5. scores[b] = q[b] @ k[b]^T  (K=640 -> NT=20)
  gemm_pipe<20, float, false><<<dim3(SEQ / 128, SEQ / 128, NBATCH), 256, 0, stream>>>(
      qkv, qkv + QKV_S, scores, nullptr, DIM, SEQ, SEQ,
      (long)SEQ * DIM, (long)SEQ * DIM, (long)SEQ * SEQ);

  // 6. causal softmax -> P bf16
  softmax_kernel<<<MROWS / 4, 256, 0, stream>>>(scores, P);

  // 7. attn[b] = P[b] @ vT[b]^T  (K=256 -> NT=8)
  gemm_pipe<8, bf16, false><<<dim3(SEQ / 128, DIM / 128, NBATCH), 256, 0, stream>>>(
      P, vT, attn, nullptr, SEQ, DIM, DIM,
      (long)SEQ * SEQ, (long)DIM * SEQ, (long)SEQ * DIM);

  // 8. logits = attn @ w_out^T + b_out  (8-wave high-occupancy 128x128)
  gemm8<<<dim3(MROWS / 128, VPAD / 128), 512, 0, stream>>>(attn, wout_bf, out, b_out);
}